// Round 6
// baseline (63770.172 us; speedup 1.0000x reference)
//
#include <hip/hip_runtime.h>
#include <cmath>

#define NN   68     // nodes
#define NPAD 72     // E buffer padded to 2 chunks of 36 (144 B, 16B-aligned)
#define HALF 36     // K-chunk per thread
#define NT   136    // 2 threads per node (K-split), 3 waves on 3 SIMDs

// lane XOR 1 within quad via DPP quad_perm [1,0,3,2] -- pure VALU, no LDS
__device__ __forceinline__ float dpp_xor1(float x) {
    return __int_as_float(
        __builtin_amdgcn_mov_dpp(__float_as_int(x), 0xB1, 0xF, 0xF, true));
}

#if __has_builtin(__builtin_amdgcn_exp2f)
#define FAST_EXP2(x) __builtin_amdgcn_exp2f(x)
#else
#define FAST_EXP2(x) exp2f(x)
#endif
#define FAST_RCP(x) __builtin_amdgcn_rcpf(x)

#define MAC(q, e)                 \
    a0 = fmaf(q.x, e.x, a0);      \
    a1 = fmaf(q.y, e.y, a1);      \
    a2 = fmaf(q.z, e.z, a2);      \
    a3 = fmaf(q.w, e.w, a3);

// Opaque register pin. Round-5 lesson: pinning ONCE outside the loop does
// nothing -- the allocator parks loop-invariants in AGPRs afterwards, and
// every FMA then pays a v_accvgpr_read shuttle. Pinning INSIDE the loop
// forces arch-VGPR residency at every iteration.
#define PIN4(q) asm volatile("" : "+v"(q.x), "+v"(q.y), "+v"(q.z), "+v"(q.w))

__global__ __launch_bounds__(NT, 1)
void nmm_kernel(const float* __restrict__ params,
                const float* __restrict__ Cjk,
                const float* __restrict__ y0,
                float* __restrict__ out,
                const int num_steps)
{
#pragma clang fp contract(off)
    const int tid = threadIdx.x;
    const int j   = tid >> 1;    // node 0..67
    const int s   = tid & 1;     // K-half 0/1

    __shared__ __align__(16) float E_lds[2][NPAD];

    const float tau_e = params[0], tau_i = params[1];
    const float P1 = params[2], P2 = params[3], P3 = params[4];
    const float P4 = params[5], P5 = params[6], Pp = params[7];
    const float kE = params[8], kI = params[9];

    const float LOG2E = 1.4426950408889634f;
    const float kE2 = -1.3f * LOG2E, bE2 = (1.3f * 4.0f) * LOG2E;
    const float kI2 = -2.0f * LOG2E, bI2 = (2.0f * 3.7f) * LOG2E;
    const float s0E = 1.0f / (1.0f + expf(5.2f));
    const float s0I = 1.0f / (1.0f + expf(7.4f));
    const float inv_te = 1.0f / tau_e, inv_ti = 1.0f / tau_i;

    // C-row half chunk -> 9 float4s
    const float* crow = Cjk + j * NN + s * HALF;
    float4 q0 = *(const float4*)(crow +  0);
    float4 q1 = *(const float4*)(crow +  4);
    float4 q2 = *(const float4*)(crow +  8);
    float4 q3 = *(const float4*)(crow + 12);
    float4 q4 = *(const float4*)(crow + 16);
    float4 q5 = *(const float4*)(crow + 20);
    float4 q6 = *(const float4*)(crow + 24);
    float4 q7 = *(const float4*)(crow + 28);
    float4 q8 = (s == 0) ? *(const float4*)(crow + 32)
                         : make_float4(0.f, 0.f, 0.f, 0.f);

    if (tid < NPAD) {
        E_lds[0][tid] = (tid < NN) ? y0[tid] : 0.0f;
        E_lds[1][tid] = 0.0f;
    }
    float E = y0[j];
    float I = y0[NN + j];
    asm volatile("s_waitcnt lgkmcnt(0)\ns_barrier" ::: "memory");

    // conn_0 = C @ E_0
    float conn;
    {
        const float* eb = &E_lds[0][s * HALF];
        const float4 e0 = ((const float4*)eb)[0], e1 = ((const float4*)eb)[1],
                     e2 = ((const float4*)eb)[2], e3 = ((const float4*)eb)[3],
                     e4 = ((const float4*)eb)[4], e5 = ((const float4*)eb)[5],
                     e6 = ((const float4*)eb)[6], e7 = ((const float4*)eb)[7],
                     e8 = ((const float4*)eb)[8];
        float a0 = 0.f, a1 = 0.f, a2 = 0.f, a3 = 0.f;
        MAC(q0, e0) MAC(q1, e1) MAC(q2, e2) MAC(q3, e3) MAC(q4, e4)
        MAC(q5, e5) MAC(q6, e6) MAC(q7, e7) MAC(q8, e8)
        const float p = (a0 + a1) + (a2 + a3);
        conn = p + dpp_xor1(p);
    }

    float* op = out + (size_t)j * (size_t)num_steps;

    for (int t = 0; t < num_steps; ++t) {
        const int cur = t & 1;

        // in-loop pin: C-quads must be arch-VGPRs HERE, every iteration
        PIN4(q0); PIN4(q1); PIN4(q2); PIN4(q3); PIN4(q4);
        PIN4(q5); PIN4(q6); PIN4(q7); PIN4(q8);

        // 1) E_t reads issue first; LDS latency hides under elementwise
        const float* eb = &E_lds[cur][s * HALF];
        float4 e0 = ((const float4*)eb)[0], e1 = ((const float4*)eb)[1],
               e2 = ((const float4*)eb)[2], e3 = ((const float4*)eb)[3],
               e4 = ((const float4*)eb)[4], e5 = ((const float4*)eb)[5],
               e6 = ((const float4*)eb)[6], e7 = ((const float4*)eb)[7],
               e8 = ((const float4*)eb)[8];
        PIN4(e0); PIN4(e1); PIN4(e2); PIN4(e3); PIN4(e4);
        PIN4(e5); PIN4(e6); PIN4(e7); PIN4(e8);

        // 2) elementwise update with conn_t (identical to round-4 math)
        const float xE = P1 * E - P2 * I + P5 * conn + Pp;
        const float Se = FAST_RCP(1.0f + FAST_EXP2(fmaf(kE2, xE, bE2))) - s0E;
        const float xI = P3 * E - P4 * I;                          // Q = 0
        const float Si = FAST_RCP(1.0f + FAST_EXP2(fmaf(kI2, xI, bI2))) - s0I;
        const float En = fmaf(fmaf(kE - E, Se, -E), inv_te, E);
        const float In = fmaf(fmaf(kI - I, Si, -I), inv_ti, I);

        // 3) publish (both lanes same-addr same-value LDS write: free)
        E_lds[cur ^ 1][j] = En;
        if (s == 0) op[t] = En - In;     // fire-and-forget, never drained

        // 4) conn_{t+1} = C @ E_t
        float a0 = 0.f, a1 = 0.f, a2 = 0.f, a3 = 0.f;
        MAC(q0, e0) MAC(q1, e1) MAC(q2, e2) MAC(q3, e3) MAC(q4, e4)
        MAC(q5, e5) MAC(q6, e6) MAC(q7, e7) MAC(q8, e8)
        const float p = (a0 + a1) + (a2 + a3);
        conn = p + dpp_xor1(p);

        E = En; I = In;
        // LDS-only barrier: never drains the output stores (vmcnt untouched)
        asm volatile("s_waitcnt lgkmcnt(0)\ns_barrier" ::: "memory");
    }
}

extern "C" void kernel_launch(void* const* d_in, const int* in_sizes, int n_in,
                              void* d_out, int out_size, void* d_ws, size_t ws_size,
                              hipStream_t stream) {
    const float* params = (const float*)d_in[0];
    const float* Cjk    = (const float*)d_in[1];
    const float* y0     = (const float*)d_in[2];
    const int num_steps = out_size / NN;

    nmm_kernel<<<dim3(1), dim3(NT), 0, stream>>>(
        params, Cjk, y0, (float*)d_out, num_steps);
}